// Round 15
// baseline (152.605 us; speedup 1.0000x reference)
//
#include <hip/hip_runtime.h>

// Problem sizes (fixed)
#define NB   32
#define CI   256
#define HH   56
#define WW   56
#define PL   128   // planes (conv1/conv2 out channels)
#define HO   28
#define WO   28
#define CO   512   // out_planes
#define NPIX (HH * WW)   // 3136
#define NOUT (HO * WO)   // 784
#define FIXCAP 65536u
#define MARGIN1 3e-3f
#define MARGIN3 6e-3f

typedef unsigned long long u64;
typedef __attribute__((ext_vector_type(8))) short short8v;   // 8 bf16 (4 VGPR)
typedef __attribute__((ext_vector_type(4))) float f32x4;

// ============ exact f32 -> (hi,lo) bf16 split, RNE both ============
__device__ __forceinline__ unsigned cvt_split(float f) {
  unsigned u = __float_as_uint(f);
  unsigned hi = (u + 0x7FFFu + ((u >> 16) & 1u)) >> 16;
  float r = f - __uint_as_float(hi << 16);            // exact (Sterbenz)
  unsigned ur = __float_as_uint(r);
  unsigned lo = (ur + 0x7FFFu + ((ur >> 16) & 1u)) >> 16;
  return hi | (lo << 16);                             // low16 = hi part, high16 = lo part
}

// ============ async global->LDS, 16B per lane ============
__device__ __forceinline__ void gload_lds16(const unsigned* g, unsigned* l) {
  __builtin_amdgcn_global_load_lds(
      (const __attribute__((address_space(1))) void*)g,
      (__attribute__((address_space(3))) void*)l, 16, 0, 0);
}

// ---------------- K0: pack weights + BN constants ----------------
__global__ __launch_bounds__(256) void pack_kernel(
    const float* __restrict__ W1, const float* __restrict__ W2,
    const float* __restrict__ W3, const float* __restrict__ Wsc,
    const float* __restrict__ g1, const float* __restrict__ b1,
    const float* __restrict__ m1, const float* __restrict__ v1,
    const float* __restrict__ g3, const float* __restrict__ b3,
    const float* __restrict__ m3, const float* __restrict__ v3,
    const float* __restrict__ gs, const float* __restrict__ bs,
    const float* __restrict__ ms, const float* __restrict__ vs,
    float* __restrict__ w1f, float* __restrict__ wscf,
    u64* __restrict__ w2b, u64* __restrict__ w3b,
    float* __restrict__ T1f, double* __restrict__ bn1d,
    float* __restrict__ bn3f, double* __restrict__ bn3d,
    unsigned* __restrict__ w1k, unsigned* __restrict__ wsck,
    unsigned* __restrict__ cnts) {
  int tid = blockIdx.x * 256 + threadIdx.x;
  int lane = tid & 63;
  if (tid < 32768) {
    int co = tid & 127, ci = tid >> 7;
    w1f[tid] = (W1[co * 256 + ci] >= 0.f) ? 1.0f : -1.0f;
  } else if (tid < 163840) {
    int i = tid - 32768;
    int co = i & 511, ci = i >> 9;
    wscf[i] = (Wsc[co * 256 + ci] >= 0.f) ? 1.0f : -1.0f;
  } else if (tid < 311296) {
    int wv = (tid - 163840) >> 6;       // co*18 + tap*2 + word
    int co = wv / 18, r = wv % 18;
    int tap = r >> 1, word = r & 1;
    int ci = word * 64 + lane;
    bool pred = W2[(co * 128 + ci) * 9 + tap] >= 0.f;
    u64 m = __ballot(pred);
    if (lane == 0) w2b[(co * 9 + tap) * 2 + word] = m;
  } else if (tid < 376832) {
    int wv = (tid - 311296) >> 6;       // co*2 + word
    int co = wv >> 1, word = wv & 1;
    int ci = word * 64 + lane;
    bool pred = W3[co * 128 + ci] >= 0.f;
    u64 m = __ballot(pred);
    if (lane == 0) w3b[co * 2 + word] = m;
  } else if (tid < 376960) {
    int co = tid - 376832;
    double s = (double)g1[co] / sqrt((double)v1[co] + 1e-5);
    double m = (double)m1[co], b = (double)b1[co];
    bn1d[co] = s; bn1d[128 + co] = m; bn1d[256 + co] = b;
    T1f[co] = (float)(m - b / s);
  } else if (tid < 377472) {
    int co = tid - 376960;
    double ss = (double)gs[co] / sqrt((double)vs[co] + 1e-5);
    double s3 = (double)g3[co] / sqrt((double)v3[co] + 1e-5);
    double C = (double)bs[co] + (double)b3[co]
             - (double)ms[co] * ss - (double)m3[co] * s3;
    bn3d[co] = ss; bn3d[512 + co] = s3; bn3d[1024 + co] = C;
    bn3f[co] = (float)ss; bn3f[512 + co] = (float)s3; bn3f[1024 + co] = (float)C;
  } else if (tid < 410240) {
    int i = tid - 377472;                 // co*256 + ci, co<128
    int co = i >> 8, ci = i & 255;
    unsigned b = (W1[co * 256 + ci] >= 0.f) ? 0x3F80u : 0xBF80u;
    int kst = ci >> 5, u = ci & 31;
    w1k[(size_t)kst * (128 * 32) + co * 32 + (u ^ ((co & 7) << 2))] = b | (b << 16);
  } else if (tid < 541312) {
    int i = tid - 410240;                 // co*256 + ci, co<512
    int co = i >> 8, ci = i & 255;
    unsigned b = (Wsc[co * 256 + ci] >= 0.f) ? 0x3F80u : 0xBF80u;
    int kst = ci >> 5, u = ci & 31;
    wsck[(size_t)kst * (512 * 32) + co * 32 + (u ^ ((co & 7) << 2))] = b | (b << 16);
  } else if (tid < 541314) {
    cnts[tid - 541312] = 0;
  }
}

// ============ f64 recheck paths (overflow/fallback only) ============
__device__ __noinline__ bool recheck_conv1(const float* __restrict__ xg,
                                           const float* __restrict__ w1f,
                                           const double* __restrict__ bn1d,
                                           int co) {
  double a = 0.0;
  for (int ci = 0; ci < 256; ++ci)
    a = fma((double)w1f[ci * 128 + co], (double)xg[(size_t)ci * NPIX], a);
  double val = (a - bn1d[128 + co]) * bn1d[co] + bn1d[256 + co];
  return val >= 0.0;
}

__device__ __noinline__ bool recheck_sc3(const float* __restrict__ xg,
                                         const float* __restrict__ wscf,
                                         const double* __restrict__ bn3d,
                                         int co, int y3) {
  double a = 0.0;
  for (int ci = 0; ci < 256; ++ci)
    a = fma((double)wscf[ci * 512 + co], (double)xg[(size_t)ci * NPIX], a);
  double val = a * bn3d[co] + (double)y3 * bn3d[512 + co] + bn3d[1024 + co];
  return val >= 0.0;
}

// ---------------- K1: conv1 GEMM, fused transpose, depth-3 x prefetch ------
__global__ __launch_bounds__(256) void conv1_mfma_kernel(
    const float* __restrict__ x, const unsigned* __restrict__ w1k,
    const float* __restrict__ w1f,
    const float* __restrict__ T1f, const double* __restrict__ bn1d,
    uint2* __restrict__ fix1, unsigned* __restrict__ cnts,
    u64* __restrict__ a1b, unsigned* __restrict__ xTk2) {
  __shared__ unsigned ldsB[2][2048];    // 16 KB

  int n = blockIdx.x / 49, pxt = blockIdx.x % 49;
  int px0 = pxt * 64;
  int t = threadIdx.x, w = t >> 6, lane = t & 63;
  int l16 = lane >> 4, llo = lane & 15;
  int sA = (llo & 7) << 2;
  int coL = w * 32 + llo;

  const float* xb = x + (size_t)n * CI * NPIX + px0;
  const unsigned* wb = w1k + (size_t)coL * 32;
  int offA[2][2];
#pragma unroll
  for (int cf = 0; cf < 2; ++cf)
#pragma unroll
    for (int ks = 0; ks < 2; ++ks)
      offA[cf][ks] = cf * 512 + ((ks * 16 + l16 * 4) ^ sA);

  // B-stage slots
  int u0 = t >> 4, u1 = u0 + 16, q = t & 15;
  int pxq = q * 4;
  int sBw[4];
#pragma unroll
  for (int j = 0; j < 4; ++j) sBw[j] = (((pxq + j) >> 1) & 7) << 2;

  // xTk2 bounce slot
  int bg = t & 7, be = t >> 3;
  int bp = px0 + 2 * be;
  int bh = bp / WW;
  bool bok = (bh & 1) == 0;
  int bpl = (bh >> 1) * WO + (bp % WW) / 2;
  int brd = (2 * be) * 32 + ((4 * bg) ^ ((be & 7) << 2));
  size_t bwr = (size_t)bpl * 32 + ((4 * bg) ^ ((bpl & 7) << 2));
  unsigned* xTbase = xTk2 + (size_t)(n * 8) * NOUT * 32;

  f32x4 acc[2][4] = {};

  // x prefetch ring: 4 named slots, depth 3 (tile m loaded at iter m-3)
  float4 Pa[4], Pb[4];
#pragma unroll
  for (int k = 0; k < 3; ++k) {
    Pa[k] = *(const float4*)(xb + (size_t)(k * 32 + u0) * NPIX + pxq);
    Pb[k] = *(const float4*)(xb + (size_t)(k * 32 + u1) * NPIX + pxq);
  }

  // A-frag ping-pong
  short8v aP[2][2][2];
#pragma unroll
  for (int cf = 0; cf < 2; ++cf)
#pragma unroll
    for (int ks = 0; ks < 2; ++ks)
      aP[0][cf][ks] = *(const short8v*)(wb + offA[cf][ks]);

  // stage tile 0 into buf0
  {
    unsigned wd0[4], wd1[4];
    wd0[0] = cvt_split(Pa[0].x); wd0[1] = cvt_split(Pa[0].y);
    wd0[2] = cvt_split(Pa[0].z); wd0[3] = cvt_split(Pa[0].w);
    wd1[0] = cvt_split(Pb[0].x); wd1[1] = cvt_split(Pb[0].y);
    wd1[2] = cvt_split(Pb[0].z); wd1[3] = cvt_split(Pb[0].w);
#pragma unroll
    for (int j = 0; j < 4; ++j) {
      ldsB[0][(pxq + j) * 32 + (u0 ^ sBw[j])] = wd0[j];
      ldsB[0][(pxq + j) * 32 + (u1 ^ sBw[j])] = wd1[j];
    }
  }
  asm volatile("s_waitcnt lgkmcnt(0)" ::: "memory");
  __builtin_amdgcn_s_barrier();

#pragma unroll
  for (int kst = 0; kst < 8; ++kst) {
    int cur = kst & 1;
    // issue prefetches EARLY, pin with sched_barrier
    if (kst + 3 < 8) {
      Pa[(kst + 3) & 3] = *(const float4*)(xb + (size_t)((kst + 3) * 32 + u0) * NPIX + pxq);
      Pb[(kst + 3) & 3] = *(const float4*)(xb + (size_t)((kst + 3) * 32 + u1) * NPIX + pxq);
    }
    if (kst + 1 < 8) {
#pragma unroll
      for (int cf = 0; cf < 2; ++cf)
#pragma unroll
        for (int ks = 0; ks < 2; ++ks)
          aP[(kst + 1) & 1][cf][ks] =
              *(const short8v*)(wb + (kst + 1) * 4096 + offA[cf][ks]);
    }
    __builtin_amdgcn_sched_barrier(0);

    // MFMA on current buffer
#pragma unroll
    for (int ks = 0; ks < 2; ++ks) {
      int kb = ks * 16 + l16 * 4;
#pragma unroll
      for (int pf = 0; pf < 4; ++pf) {
        int pxl = pf * 16 + llo;
        int sB = ((pxl >> 1) & 7) << 2;
        short8v bv = *(const short8v*)(&ldsB[cur][pxl * 32 + (kb ^ sB)]);
        acc[0][pf] = __builtin_amdgcn_mfma_f32_16x16x32_bf16(aP[cur][0][ks], bv, acc[0][pf], 0, 0, 0);
        acc[1][pf] = __builtin_amdgcn_mfma_f32_16x16x32_bf16(aP[cur][1][ks], bv, acc[1][pf], 0, 0, 0);
      }
    }
    // coalesced xTk2 bounce from current buffer (fire & forget store)
    if (bok) {
      uint4 o = *(const uint4*)(&ldsB[cur][brd]);
      *(uint4*)(xTbase + (size_t)kst * (NOUT * 32) + bwr) = o;
    }
    // stage next tile from regs loaded 3 iterations ago
    if (kst < 7) {
      unsigned wd0[4], wd1[4];
      wd0[0] = cvt_split(Pa[(kst + 1) & 3].x); wd0[1] = cvt_split(Pa[(kst + 1) & 3].y);
      wd0[2] = cvt_split(Pa[(kst + 1) & 3].z); wd0[3] = cvt_split(Pa[(kst + 1) & 3].w);
      wd1[0] = cvt_split(Pb[(kst + 1) & 3].x); wd1[1] = cvt_split(Pb[(kst + 1) & 3].y);
      wd1[2] = cvt_split(Pb[(kst + 1) & 3].z); wd1[3] = cvt_split(Pb[(kst + 1) & 3].w);
#pragma unroll
      for (int j = 0; j < 4; ++j) {
        ldsB[cur ^ 1][(pxq + j) * 32 + (u0 ^ sBw[j])] = wd0[j];
        ldsB[cur ^ 1][(pxq + j) * 32 + (u1 ^ sBw[j])] = wd1[j];
      }
    }
    asm volatile("s_waitcnt lgkmcnt(0)" ::: "memory");
    __builtin_amdgcn_s_barrier();
  }

  // epilogue: sign + margin->append -> swizzled LDS bytes -> bitmask words
  unsigned char* ldsS = (unsigned char*)&ldsB[0][0];   // 8192 B
  int co_b = w * 32;
  float Tv[2][4];
#pragma unroll
  for (int cf = 0; cf < 2; ++cf)
#pragma unroll
    for (int r = 0; r < 4; ++r)
      Tv[cf][r] = T1f[co_b + cf * 16 + l16 * 4 + r];

#pragma unroll
  for (int cf = 0; cf < 2; ++cf)
#pragma unroll
    for (int pf = 0; pf < 4; ++pf) {
      int px_l = pf * 16 + llo;
#pragma unroll
      for (int r = 0; r < 4; ++r) {
        int co = co_b + cf * 16 + l16 * 4 + r;
        float d = acc[cf][pf][r] - Tv[cf][r];
        bool pos = d >= 0.f;
        if (__builtin_fabsf(d) < MARGIN1) {
          unsigned idx = atomicAdd(&cnts[0], 1u);
          if (idx < FIXCAP) fix1[idx] = make_uint2((unsigned)(n * NPIX + px0 + px_l),
                                                   (unsigned)co);
          else pos = recheck_conv1(x + (size_t)n * CI * NPIX + px0 + px_l,
                                   w1f, bn1d, co);
        }
        ldsS[px_l * 128 + (co ^ ((px_l & 7) << 2))] = pos ? 1 : 0;
      }
    }
  __syncthreads();

  if (t < 64) {
    int px = t;
    const unsigned* ls = (const unsigned*)ldsS;
    u64 wd0 = 0, wd1 = 0;
#pragma unroll
    for (int k = 0; k < 16; ++k) {
      unsigned v = ls[px * 32 + (k ^ (px & 7))];
      unsigned nib = (((v & 0x01010101u) * 0x01020408u) >> 24) & 0xFu;
      wd0 |= (u64)nib << (4 * k);
    }
#pragma unroll
    for (int k = 16; k < 32; ++k) {
      unsigned v = ls[px * 32 + (k ^ (px & 7))];
      unsigned nib = (((v & 0x01010101u) * 0x01020408u) >> 24) & 0xFu;
      wd1 |= (u64)nib << (4 * (k - 16));
    }
    u64* ap = a1b + (size_t)(n * NPIX + px0 + px) * 2;
    ap[0] = wd0; ap[1] = wd1;
  }
}

// ---------------- F1: wave-parallel f64 fixup of a1b bits ----------------
__global__ __launch_bounds__(256) void fixup1_kernel(
    const float* __restrict__ x, const float* __restrict__ w1f,
    const double* __restrict__ bn1d, const uint2* __restrict__ fix1,
    const unsigned* __restrict__ cnts, u64* __restrict__ a1b) {
  unsigned cnt = cnts[0]; if (cnt > FIXCAP) cnt = FIXCAP;
  int nw = gridDim.x * 4;
  int gw = blockIdx.x * 4 + (threadIdx.x >> 6);
  int lane = threadIdx.x & 63;
  for (unsigned i = gw; i < cnt; i += nw) {
    uint2 it = fix1[i];
    int np = (int)it.x, co = (int)it.y;
    int n = np / NPIX, p = np % NPIX;
    const float* xg = x + (size_t)n * CI * NPIX + p;
    double s = 0.0;
#pragma unroll
    for (int j = 0; j < 4; ++j) {
      int ci = lane * 4 + j;
      s = fma((double)w1f[ci * 128 + co], (double)xg[(size_t)ci * NPIX], s);
    }
    for (int off = 32; off; off >>= 1) s += __shfl_down(s, off);
    if (lane == 0) {
      double val = (s - bn1d[128 + co]) * bn1d[co] + bn1d[256 + co];
      u64* ap = a1b + (size_t)np * 2 + (co >> 6);
      u64 bit = 1ull << (co & 63);
      if (val >= 0.0) atomicOr(ap, bit); else atomicAnd(ap, ~bit);
    }
  }
}

// ---------------- K2: conv2 (3x3 s2 p1, XNOR-popcount) + bn2 + sign --------
__global__ __launch_bounds__(256) void conv2_kernel(
    const u64* __restrict__ a1b, const u64* __restrict__ w2b,
    const float* __restrict__ g2, const float* __restrict__ b2,
    const float* __restrict__ m2, const float* __restrict__ v2,
    u64* __restrict__ a2b) {
  __shared__ u64 lw2[128 * 9 * 2];   // 18432 B
  int t = threadIdx.x;
  for (int k = 0; k < 9; ++k) lw2[t * 9 + k] = w2b[t * 9 + k];
  __syncthreads();

  int p = blockIdx.x * 4 + (t >> 6);    // 0..25087
  int lane = t & 63;
  int n = p / NOUT, r = p % NOUT;
  int ho = r / WO, wo = r % WO;

  int y0 = 0, y1 = 0;
  for (int kh = 0; kh < 3; ++kh) {
    int ih = 2 * ho - 1 + kh;
    if (ih < 0) continue;
    for (int kw = 0; kw < 3; ++kw) {
      int iw = 2 * wo - 1 + kw;
      if (iw < 0) continue;
      const u64* ap = a1b + ((size_t)(n * HH + ih) * WW + iw) * 2;
      u64 a0 = ap[0], a1v = ap[1];
      int tap = kh * 3 + kw;
      u64 wa = lw2[lane * 18 + tap * 2], wb = lw2[lane * 18 + tap * 2 + 1];
      y0 += 128 - 2 * (__popcll(a0 ^ wa) + __popcll(a1v ^ wb));
      wa = lw2[(lane + 64) * 18 + tap * 2]; wb = lw2[(lane + 64) * 18 + tap * 2 + 1];
      y1 += 128 - 2 * (__popcll(a0 ^ wa) + __popcll(a1v ^ wb));
    }
  }

  int co = lane;
  double inv = 1.0 / sqrt((double)v2[co] + 1e-5);
  bool c0 = (((double)y0 - (double)m2[co]) * ((double)g2[co] * inv) + (double)b2[co]) >= 0.0;
  co = lane + 64;
  inv = 1.0 / sqrt((double)v2[co] + 1e-5);
  bool c1 = (((double)y1 - (double)m2[co]) * ((double)g2[co] * inv) + (double)b2[co]) >= 0.0;

  u64 word0 = __ballot(c0);
  u64 word1 = __ballot(c1);
  if (lane == 0) {
    a2b[(size_t)p * 2] = word0;
    a2b[(size_t)p * 2 + 1] = word1;
  }
}

// ---------------- K3: shortcut GEMM, depth-2 counted-vmcnt pipeline --------
// 3 LDS buffers; per iter issue A(k+1) then B(k+2); drain through A(k) ->
// vmcnt leaves B(k+1)+A(k+1)+B(k+2)=12. B tiles fly 2 full iterations.
__global__ __launch_bounds__(256) void sc3_mfma_kernel(
    const unsigned* __restrict__ xTk2, const unsigned* __restrict__ wsck,
    const u64* __restrict__ a2b, const u64* __restrict__ w3b,
    const float* __restrict__ bn3f,
    uint2* __restrict__ fix3, unsigned* __restrict__ cnts,
    float* __restrict__ out) {
  __shared__ unsigned ldsB2[3][4096];   // 48 KB

  int b = blockIdx.x;
  int cob = b & 3; int r2 = b >> 2; int pxt = r2 % 7; int n = r2 / 7;
  int px0 = pxt * 112;
  int t = threadIdx.x, w = t >> 6, lane = t & 63;
  int l16 = lane >> 4, llo = lane & 15;
  int sA = (llo & 7) << 2;
  int coL = w * 32 + llo;

  const unsigned* wb = wsck + (size_t)(cob * 128 + coL) * 32;
  int offA[2][2];
#pragma unroll
  for (int cf = 0; cf < 2; ++cf)
#pragma unroll
    for (int ks = 0; ks < 2; ++ks)
      offA[cf][ks] = cf * 512 + ((ks * 16 + l16 * 4) ^ sA);

  const unsigned* gb0 = xTk2 + ((size_t)n * 8 * NOUT + px0) * 32 + lane * 4;

  f32x4 acc[2][7] = {};
  short8v aP[2][2][2];

  // prologue: B0 -> buf0, B1 -> buf1, A0
#pragma unroll
  for (int i = 0; i < 4; ++i) {
    int idx = i * 4 + w;
    const unsigned* src = gb0 + (idx < 14 ? idx * 256 : 0);
    gload_lds16(src, &ldsB2[0][idx * 256]);
  }
#pragma unroll
  for (int i = 0; i < 4; ++i) {
    int idx = i * 4 + w;
    const unsigned* gb = gb0 + (size_t)(NOUT * 32);
    const unsigned* src = gb + (idx < 14 ? idx * 256 : 0);
    gload_lds16(src, &ldsB2[1][idx * 256]);
  }
#pragma unroll
  for (int cf = 0; cf < 2; ++cf)
#pragma unroll
    for (int ks = 0; ks < 2; ++ks)
      aP[0][cf][ks] = *(const short8v*)(wb + offA[cf][ks]);

#pragma unroll
  for (int kst = 0; kst < 8; ++kst) {
    int cur = kst % 3;
    // issue A(k+1) first, then B(k+2)
    if (kst + 1 < 8) {
#pragma unroll
      for (int cf = 0; cf < 2; ++cf)
#pragma unroll
        for (int ks = 0; ks < 2; ++ks)
          aP[(kst + 1) & 1][cf][ks] =
              *(const short8v*)(wb + (kst + 1) * 16384 + offA[cf][ks]);
    }
    if (kst + 2 < 8) {
      const unsigned* gb = gb0 + (size_t)(kst + 2) * (NOUT * 32);
#pragma unroll
      for (int i = 0; i < 4; ++i) {
        int idx = i * 4 + w;
        const unsigned* src = gb + (idx < 14 ? idx * 256 : 0);
        gload_lds16(src, &ldsB2[(kst + 2) % 3][idx * 256]);
      }
    }
    // counted wait: drain through A(k) and B(k)
    if (kst == 0) asm volatile("s_waitcnt vmcnt(8)" ::: "memory");
    else if (kst <= 5) asm volatile("s_waitcnt vmcnt(12)" ::: "memory");
    else if (kst == 6) asm volatile("s_waitcnt vmcnt(8)" ::: "memory");
    else asm volatile("s_waitcnt vmcnt(0)" ::: "memory");
    __builtin_amdgcn_s_barrier();

#pragma unroll
    for (int ks = 0; ks < 2; ++ks) {
      int kb = ks * 16 + l16 * 4;
#pragma unroll
      for (int pf = 0; pf < 7; ++pf) {
        short8v bv = *(const short8v*)(&ldsB2[cur][(pf * 16 + llo) * 32 + (kb ^ sA)]);
        acc[0][pf] = __builtin_amdgcn_mfma_f32_16x16x32_bf16(aP[kst & 1][0][ks], bv, acc[0][pf], 0, 0, 0);
        acc[1][pf] = __builtin_amdgcn_mfma_f32_16x16x32_bf16(aP[kst & 1][1][ks], bv, acc[1][pf], 0, 0, 0);
      }
    }
    // bottom barrier: protect buf[cur] (overwritten by B(k+3) issued at k+1)
    __builtin_amdgcn_s_barrier();
  }

  // epilogue: conv3 popcount + fused BNs + sign (+ rare list-append)
  int co_base = cob * 128 + w * 32;
  int pl[7];
  u64 a20[7], a21[7];
#pragma unroll
  for (int pf = 0; pf < 7; ++pf) {
    pl[pf] = px0 + pf * 16 + llo;
    const u64* ap = a2b + (size_t)(n * NOUT + pl[pf]) * 2;
    a20[pf] = ap[0]; a21[pf] = ap[1];
  }

#pragma unroll
  for (int cf = 0; cf < 2; ++cf) {
    float ssv[4], s3v[4], Cv[4];
    u64 w30[4], w31[4];
#pragma unroll
    for (int r = 0; r < 4; ++r) {
      int co = co_base + cf * 16 + l16 * 4 + r;
      ssv[r] = bn3f[co]; s3v[r] = bn3f[512 + co]; Cv[r] = bn3f[1024 + co];
      w30[r] = w3b[co * 2]; w31[r] = w3b[co * 2 + 1];
    }
#pragma unroll
    for (int pf = 0; pf < 7; ++pf) {
#pragma unroll
      for (int r = 0; r < 4; ++r) {
        int co = co_base + cf * 16 + l16 * 4 + r;
        int y3 = 128 - 2 * (int)(__popcll(a20[pf] ^ w30[r]) +
                                 __popcll(a21[pf] ^ w31[r]));
        float val = fmaf(acc[cf][pf][r], ssv[r],
                         fmaf((float)y3, s3v[r], Cv[r]));
        bool pos = val >= 0.f;
        if (__builtin_fabsf(val) < MARGIN3) {
          unsigned idx = atomicAdd(&cnts[1], 1u);
          if (idx < FIXCAP)
            fix3[idx] = make_uint2((unsigned)(n * NOUT + pl[pf]),
                                   (unsigned)co | ((unsigned)(y3 + 256) << 16));
        }
        out[(size_t)(n * CO + co) * NOUT + pl[pf]] = pos ? 1.0f : -1.0f;
      }
    }
  }
}

// ---------------- F3: wave-parallel f64 fixup of out values ----------------
__global__ __launch_bounds__(256) void fixup3_kernel(
    const float* __restrict__ x, const float* __restrict__ wscf,
    const double* __restrict__ bn3d, const uint2* __restrict__ fix3,
    const unsigned* __restrict__ cnts, float* __restrict__ out) {
  unsigned cnt = cnts[1]; if (cnt > FIXCAP) cnt = FIXCAP;
  int nw = gridDim.x * 4;
  int gw = blockIdx.x * 4 + (threadIdx.x >> 6);
  int lane = threadIdx.x & 63;
  for (unsigned i = gw; i < cnt; i += nw) {
    uint2 it = fix3[i];
    int npl = (int)it.x;
    int co = (int)(it.y & 0xFFFFu);
    int y3 = (int)(it.y >> 16) - 256;
    int n = npl / NOUT, pl = npl % NOUT;
    int ho = pl / WO, wo = pl % WO;
    const float* xg = x + (size_t)n * CI * NPIX + ho * 112 + wo * 2;
    double s = 0.0;
#pragma unroll
    for (int j = 0; j < 4; ++j) {
      int ci = lane * 4 + j;
      s = fma((double)wscf[ci * 512 + co], (double)xg[(size_t)ci * NPIX], s);
    }
    for (int off = 32; off; off >>= 1) s += __shfl_down(s, off);
    if (lane == 0) {
      double val = s * bn3d[co] + (double)y3 * bn3d[512 + co] + bn3d[1024 + co];
      out[(size_t)(n * CO + co) * NOUT + pl] = (val >= 0.0) ? 1.0f : -1.0f;
    }
  }
}

// ================= fallback (R2) f32-VALU kernels =================
__global__ __launch_bounds__(256) void conv1_kernel(
    const float* __restrict__ x, const float* __restrict__ w1f,
    const float* __restrict__ T1f, const double* __restrict__ bn1d,
    u64* __restrict__ a1b) {
  __shared__ float4 xrow4[128 * WW / 4];
  __shared__ unsigned char pk[WW * 32];
  float* xrow = (float*)xrow4;

  int bid = blockIdx.x;
  int n = bid / HH, h = bid % HH;
  int t = threadIdx.x;
  int cg = t & 31, wg = t >> 5;
  int co0 = cg * 4, w0 = wg * 7;

  float acc[4][7];
#pragma unroll
  for (int c = 0; c < 4; ++c)
#pragma unroll
    for (int j = 0; j < 7; ++j) acc[c][j] = 0.f;

  for (int chunk = 0; chunk < 2; ++chunk) {
    const float4* xsrc = (const float4*)(x + (size_t)n * CI * NPIX
                                         + (size_t)chunk * 128 * NPIX + h * WW);
    for (int i = 0; i < 7; ++i) {
      int idx = i * 256 + t;
      int ci = idx / 14, f = idx % 14;
      xrow4[ci * 14 + f] = xsrc[(size_t)ci * (NPIX / 4) + f];
    }
    __syncthreads();

    const float* wp = w1f + (size_t)chunk * 128 * 128 + co0;
#pragma unroll 2
    for (int ci = 0; ci < 128; ++ci) {
      float4 wv = *(const float4*)(wp + ci * 128);
      const float* xr = xrow + ci * WW + w0;
#pragma unroll
      for (int j = 0; j < 7; ++j) {
        float xv = xr[j];
        acc[0][j] = fmaf(wv.x, xv, acc[0][j]);
        acc[1][j] = fmaf(wv.y, xv, acc[1][j]);
        acc[2][j] = fmaf(wv.z, xv, acc[2][j]);
        acc[3][j] = fmaf(wv.w, xv, acc[3][j]);
      }
    }
    __syncthreads();
  }

  float Tv[4];
#pragma unroll
  for (int c = 0; c < 4; ++c) Tv[c] = T1f[co0 + c];

  for (int j = 0; j < 7; ++j) {
    unsigned nib = 0;
    for (int c = 0; c < 4; ++c) {
      float d = acc[c][j] - Tv[c];
      bool pos;
      if (__builtin_fabsf(d) >= 1e-2f) pos = d >= 0.f;
      else pos = recheck_conv1(x + (size_t)n * CI * NPIX + h * WW + (w0 + j),
                               w1f, bn1d, co0 + c);
      nib |= ((unsigned)pos) << c;
    }
    pk[(w0 + j) * 32 + cg] = (unsigned char)nib;
  }
  __syncthreads();

  if (t < 112) {
    int w = t >> 1, half = t & 1;
    u64 word = 0;
    for (int k = 0; k < 16; ++k)
      word |= ((u64)pk[w * 32 + half * 16 + k]) << (4 * k);
    a1b[((size_t)(n * HH + h) * WW + w) * 2 + half] = word;
  }
}

__global__ __launch_bounds__(256) void sc3_kernel(
    const float* __restrict__ x, const float* __restrict__ wscf,
    const u64* __restrict__ a2b, const u64* __restrict__ w3b,
    const float* __restrict__ bn3f, const double* __restrict__ bn3d,
    float* __restrict__ out) {
  __shared__ float4 xrow4[128 * WW / 4];
  __shared__ u64 a2row[WO * 2];
  float* xrow = (float*)xrow4;

  int bid = blockIdx.x;
  int half = bid & 1;
  int tmp = bid >> 1;
  int n = tmp / HO, ho = tmp % HO;
  int t = threadIdx.x;
  int cg = t & 63, wg = t >> 6;
  int co0 = half * 256 + cg * 4, w0 = wg * 7;

  if (t < 56)
    a2row[t] = a2b[((size_t)(n * HO + ho) * WO + (t >> 1)) * 2 + (t & 1)];

  float acc[4][7];
#pragma unroll
  for (int c = 0; c < 4; ++c)
#pragma unroll
    for (int j = 0; j < 7; ++j) acc[c][j] = 0.f;

  for (int chunk = 0; chunk < 2; ++chunk) {
    const float4* xsrc = (const float4*)(x + (size_t)n * CI * NPIX
                                         + (size_t)chunk * 128 * NPIX
                                         + (2 * ho) * WW);
    for (int i = 0; i < 7; ++i) {
      int idx = i * 256 + t;
      int ci = idx / 14, f = idx % 14;
      xrow4[ci * 14 + f] = xsrc[(size_t)ci * (NPIX / 4) + f];
    }
    __syncthreads();

    const float* wp = wscf + (size_t)chunk * 128 * 512 + co0;
#pragma unroll 2
    for (int ci = 0; ci < 128; ++ci) {
      float4 wv = *(const float4*)(wp + ci * 512);
      const float* xr = xrow + ci * WW + 2 * w0;
#pragma unroll
      for (int j = 0; j < 7; ++j) {
        float xv = xr[2 * j];
        acc[0][j] = fmaf(wv.x, xv, acc[0][j]);
        acc[1][j] = fmaf(wv.y, xv, acc[1][j]);
        acc[2][j] = fmaf(wv.z, xv, acc[2][j]);
        acc[3][j] = fmaf(wv.w, xv, acc[3][j]);
      }
    }
    __syncthreads();
  }

#pragma unroll
  for (int c = 0; c < 4; ++c) {
    int co = co0 + c;
    u64 w30 = w3b[co * 2], w31 = w3b[co * 2 + 1];
    float ssf = bn3f[co], s3f = bn3f[512 + co], Cf = bn3f[1024 + co];
    float* op = out + ((size_t)(n * CO + co) * NOUT) + ho * WO + w0;
    for (int j = 0; j < 7; ++j) {
      int wo = w0 + j;
      u64 a0 = a2row[wo * 2], a1v = a2row[wo * 2 + 1];
      int y3 = 128 - 2 * (int)(__popcll(a0 ^ w30) + __popcll(a1v ^ w31));
      float val = fmaf(acc[c][j], ssf, fmaf((float)y3, s3f, Cf));
      bool pos;
      if (__builtin_fabsf(val) >= 2e-2f) pos = val >= 0.f;
      else pos = recheck_sc3(x + (size_t)n * CI * NPIX + (2 * ho) * WW + 2 * wo,
                             wscf, bn3d, co, y3);
      op[j] = pos ? 1.0f : -1.0f;
    }
  }
}

extern "C" void kernel_launch(void* const* d_in, const int* in_sizes, int n_in,
                              void* d_out, int out_size, void* d_ws, size_t ws_size,
                              hipStream_t stream) {
  const float* x   = (const float*)d_in[0];
  const float* W1  = (const float*)d_in[1];
  const float* W2  = (const float*)d_in[2];
  const float* W3  = (const float*)d_in[3];
  const float* Wsc = (const float*)d_in[4];
  const float* g1 = (const float*)d_in[5],  *b1 = (const float*)d_in[6];
  const float* m1 = (const float*)d_in[7],  *v1 = (const float*)d_in[8];
  const float* g2 = (const float*)d_in[9],  *b2 = (const float*)d_in[10];
  const float* m2 = (const float*)d_in[11], *v2 = (const float*)d_in[12];
  const float* g3 = (const float*)d_in[13], *b3 = (const float*)d_in[14];
  const float* m3 = (const float*)d_in[15], *v3 = (const float*)d_in[16];
  const float* gs = (const float*)d_in[17], *bs = (const float*)d_in[18];
  const float* ms = (const float*)d_in[19], *vs = (const float*)d_in[20];

  char* ws = (char*)d_ws;
  float*  w1f  = (float*)(ws + 0);           // 131072
  float*  wscf = (float*)(ws + 131072);      // 524288
  u64*    a1b  = (u64*)(ws + 655360);        // 1605632
  u64*    a2b  = (u64*)(ws + 2260992);       // 401408
  u64*    w2b  = (u64*)(ws + 2662400);       // 18432
  u64*    w3b  = (u64*)(ws + 2680832);       // 8192
  float*  T1f  = (float*)(ws + 2689024);     // 512
  double* bn1d = (double*)(ws + 2689536);    // 3072
  float*  bn3f = (float*)(ws + 2692608);     // 6144
  double* bn3d = (double*)(ws + 2698752);    // 12288
  unsigned* w1k  = (unsigned*)(ws + 2711040);    // 131072
  unsigned* wsck = (unsigned*)(ws + 2842112);    // 524288
  unsigned* xTk2 = (unsigned*)(ws + 3366400);    // 25690112
  uint2*    fix1 = (uint2*)(ws + 29056512);      // 524288
  uint2*    fix3 = (uint2*)(ws + 29580800);      // 524288
  unsigned* cnts = (unsigned*)(ws + 30105088);   // 256
  const size_t required = 30105344ull;           // ~28.7 MiB
  float* out = (float*)d_out;

  bool mfma_path = (ws_size >= required);
  if (!mfma_path) {   // alias mfma-only arrays into a1b region (unused then)
    w1k  = (unsigned*)a1b;
    wsck = (unsigned*)a1b + 32768;
    cnts = (unsigned*)a1b + 32768 + 131072;
  }

  hipLaunchKernelGGL(pack_kernel, dim3(2115), dim3(256), 0, stream,
                     W1, W2, W3, Wsc, g1, b1, m1, v1, g3, b3, m3, v3,
                     gs, bs, ms, vs, w1f, wscf, w2b, w3b, T1f, bn1d, bn3f, bn3d,
                     w1k, wsck, cnts);
  if (mfma_path) {
    hipLaunchKernelGGL(conv1_mfma_kernel, dim3(NB * 49), dim3(256), 0, stream,
                       x, w1k, w1f, T1f, bn1d, fix1, cnts, a1b, xTk2);
    hipLaunchKernelGGL(fixup1_kernel, dim3(256), dim3(256), 0, stream,
                       x, w1f, bn1d, fix1, cnts, a1b);
    hipLaunchKernelGGL(conv2_kernel, dim3(NB * NOUT / 4), dim3(256), 0, stream,
                       a1b, w2b, g2, b2, m2, v2, a2b);
    hipLaunchKernelGGL(sc3_mfma_kernel, dim3(NB * 7 * 4), dim3(256), 0, stream,
                       xTk2, wsck, a2b, w3b, bn3f, fix3, cnts, out);
    hipLaunchKernelGGL(fixup3_kernel, dim3(256), dim3(256), 0, stream,
                       x, wscf, bn3d, fix3, cnts, out);
  } else {
    hipLaunchKernelGGL(conv1_kernel, dim3(NB * HH), dim3(256), 0, stream,
                       x, w1f, T1f, bn1d, a1b);
    hipLaunchKernelGGL(conv2_kernel, dim3(NB * NOUT / 4), dim3(256), 0, stream,
                       a1b, w2b, g2, b2, m2, v2, a2b);
    hipLaunchKernelGGL(sc3_kernel, dim3(NB * HO * 2), dim3(256), 0, stream,
                       x, wscf, a2b, w3b, bn3f, bn3d, out);
  }
}

// Round 16
// 150.756 us; speedup vs baseline: 1.0123x; 1.0123x over previous
//
#include <hip/hip_runtime.h>

// Problem sizes (fixed)
#define NB   32
#define CI   256
#define HH   56
#define WW   56
#define PL   128   // planes (conv1/conv2 out channels)
#define HO   28
#define WO   28
#define CO   512   // out_planes
#define NPIX (HH * WW)   // 3136
#define NOUT (HO * WO)   // 784
#define FIXCAP 65536u
#define MARGIN1 3e-3f
#define MARGIN3 6e-3f

typedef unsigned long long u64;
typedef __attribute__((ext_vector_type(8))) short short8v;   // 8 bf16 (4 VGPR)
typedef __attribute__((ext_vector_type(4))) float f32x4;

// ============ exact f32 -> (hi,lo) bf16 split, RNE both ============
__device__ __forceinline__ unsigned cvt_split(float f) {
  unsigned u = __float_as_uint(f);
  unsigned hi = (u + 0x7FFFu + ((u >> 16) & 1u)) >> 16;
  float r = f - __uint_as_float(hi << 16);            // exact (Sterbenz)
  unsigned ur = __float_as_uint(r);
  unsigned lo = (ur + 0x7FFFu + ((ur >> 16) & 1u)) >> 16;
  return hi | (lo << 16);                             // low16 = hi part, high16 = lo part
}

// ============ async global->LDS, 16B per lane ============
__device__ __forceinline__ void gload_lds16(const unsigned* g, unsigned* l) {
  __builtin_amdgcn_global_load_lds(
      (const __attribute__((address_space(1))) void*)g,
      (__attribute__((address_space(3))) void*)l, 16, 0, 0);
}

// ---------------- K0: pack weights + BN constants ----------------
__global__ __launch_bounds__(256) void pack_kernel(
    const float* __restrict__ W1, const float* __restrict__ W2,
    const float* __restrict__ W3, const float* __restrict__ Wsc,
    const float* __restrict__ g1, const float* __restrict__ b1,
    const float* __restrict__ m1, const float* __restrict__ v1,
    const float* __restrict__ g3, const float* __restrict__ b3,
    const float* __restrict__ m3, const float* __restrict__ v3,
    const float* __restrict__ gs, const float* __restrict__ bs,
    const float* __restrict__ ms, const float* __restrict__ vs,
    float* __restrict__ w1f, float* __restrict__ wscf,
    u64* __restrict__ w2b, u64* __restrict__ w3b,
    float* __restrict__ T1f, double* __restrict__ bn1d,
    float* __restrict__ bn3f, double* __restrict__ bn3d,
    unsigned* __restrict__ w1k, unsigned* __restrict__ wsck,
    unsigned* __restrict__ cnts) {
  int tid = blockIdx.x * 256 + threadIdx.x;
  int lane = tid & 63;
  if (tid < 32768) {
    int co = tid & 127, ci = tid >> 7;
    w1f[tid] = (W1[co * 256 + ci] >= 0.f) ? 1.0f : -1.0f;
  } else if (tid < 163840) {
    int i = tid - 32768;
    int co = i & 511, ci = i >> 9;
    wscf[i] = (Wsc[co * 256 + ci] >= 0.f) ? 1.0f : -1.0f;
  } else if (tid < 311296) {
    int wv = (tid - 163840) >> 6;       // co*18 + tap*2 + word
    int co = wv / 18, r = wv % 18;
    int tap = r >> 1, word = r & 1;
    int ci = word * 64 + lane;
    bool pred = W2[(co * 128 + ci) * 9 + tap] >= 0.f;
    u64 m = __ballot(pred);
    if (lane == 0) w2b[(co * 9 + tap) * 2 + word] = m;
  } else if (tid < 376832) {
    int wv = (tid - 311296) >> 6;       // co*2 + word
    int co = wv >> 1, word = wv & 1;
    int ci = word * 64 + lane;
    bool pred = W3[co * 128 + ci] >= 0.f;
    u64 m = __ballot(pred);
    if (lane == 0) w3b[co * 2 + word] = m;
  } else if (tid < 376960) {
    int co = tid - 376832;
    double s = (double)g1[co] / sqrt((double)v1[co] + 1e-5);
    double m = (double)m1[co], b = (double)b1[co];
    bn1d[co] = s; bn1d[128 + co] = m; bn1d[256 + co] = b;
    T1f[co] = (float)(m - b / s);
  } else if (tid < 377472) {
    int co = tid - 376960;
    double ss = (double)gs[co] / sqrt((double)vs[co] + 1e-5);
    double s3 = (double)g3[co] / sqrt((double)v3[co] + 1e-5);
    double C = (double)bs[co] + (double)b3[co]
             - (double)ms[co] * ss - (double)m3[co] * s3;
    bn3d[co] = ss; bn3d[512 + co] = s3; bn3d[1024 + co] = C;
    bn3f[co] = (float)ss; bn3f[512 + co] = (float)s3; bn3f[1024 + co] = (float)C;
  } else if (tid < 410240) {
    int i = tid - 377472;                 // co*256 + ci, co<128
    int co = i >> 8, ci = i & 255;
    unsigned b = (W1[co * 256 + ci] >= 0.f) ? 0x3F80u : 0xBF80u;
    int kst = ci >> 5, u = ci & 31;
    w1k[(size_t)kst * (128 * 32) + co * 32 + (u ^ ((co & 7) << 2))] = b | (b << 16);
  } else if (tid < 541312) {
    int i = tid - 410240;                 // co*256 + ci, co<512
    int co = i >> 8, ci = i & 255;
    unsigned b = (Wsc[co * 256 + ci] >= 0.f) ? 0x3F80u : 0xBF80u;
    int kst = ci >> 5, u = ci & 31;
    wsck[(size_t)kst * (512 * 32) + co * 32 + (u ^ ((co & 7) << 2))] = b | (b << 16);
  } else if (tid < 541314) {
    cnts[tid - 541312] = 0;
  }
}

// ============ f64 recheck paths (overflow/fallback only) ============
__device__ __noinline__ bool recheck_conv1(const float* __restrict__ xg,
                                           const float* __restrict__ w1f,
                                           const double* __restrict__ bn1d,
                                           int co) {
  double a = 0.0;
  for (int ci = 0; ci < 256; ++ci)
    a = fma((double)w1f[ci * 128 + co], (double)xg[(size_t)ci * NPIX], a);
  double val = (a - bn1d[128 + co]) * bn1d[co] + bn1d[256 + co];
  return val >= 0.0;
}

__device__ __noinline__ bool recheck_sc3(const float* __restrict__ xg,
                                         const float* __restrict__ wscf,
                                         const double* __restrict__ bn3d,
                                         int co, int y3) {
  double a = 0.0;
  for (int ci = 0; ci < 256; ++ci)
    a = fma((double)wscf[ci * 512 + co], (double)xg[(size_t)ci * NPIX], a);
  double val = a * bn3d[co] + (double)y3 * bn3d[512 + co] + bn3d[1024 + co];
  return val >= 0.0;
}

// ---------------- K1: conv1 GEMM, fused transpose, XCD-swizzled ------------
// XCD swizzle: 1568 = 8*196; XCD k gets 4 consecutive images (all pxt) ->
// resident blocks on one XCD read contiguous DRAM regions (page locality).
__global__ __launch_bounds__(256) void conv1_mfma_kernel(
    const float* __restrict__ x, const unsigned* __restrict__ w1k,
    const float* __restrict__ w1f,
    const float* __restrict__ T1f, const double* __restrict__ bn1d,
    uint2* __restrict__ fix1, unsigned* __restrict__ cnts,
    u64* __restrict__ a1b, unsigned* __restrict__ xTk2) {
  __shared__ unsigned ldsB[2][2048];    // 16 KB

  int bid = (int)blockIdx.x;
  int l = (bid & 7) * 196 + (bid >> 3);
  int n = l / 49, pxt = l % 49;
  int px0 = pxt * 64;
  int t = threadIdx.x, w = t >> 6, lane = t & 63;
  int l16 = lane >> 4, llo = lane & 15;
  int sA = (llo & 7) << 2;
  int coL = w * 32 + llo;

  const float* xb = x + (size_t)n * CI * NPIX + px0;
  const unsigned* wb = w1k + (size_t)coL * 32;
  int offA[2][2];
#pragma unroll
  for (int cf = 0; cf < 2; ++cf)
#pragma unroll
    for (int ks = 0; ks < 2; ++ks)
      offA[cf][ks] = cf * 512 + ((ks * 16 + l16 * 4) ^ sA);

  // B-stage slots
  int u0 = t >> 4, u1 = u0 + 16, q = t & 15;
  int pxq = q * 4;
  int sBw[4];
#pragma unroll
  for (int j = 0; j < 4; ++j) sBw[j] = (((pxq + j) >> 1) & 7) << 2;

  // xTk2 bounce slot
  int bg = t & 7, be = t >> 3;
  int bp = px0 + 2 * be;
  int bh = bp / WW;
  bool bok = (bh & 1) == 0;
  int bpl = (bh >> 1) * WO + (bp % WW) / 2;
  int brd = (2 * be) * 32 + ((4 * bg) ^ ((be & 7) << 2));
  size_t bwr = (size_t)bpl * 32 + ((4 * bg) ^ ((bpl & 7) << 2));
  unsigned* xTbase = xTk2 + (size_t)(n * 8) * NOUT * 32;

  f32x4 acc[2][4] = {};

  // x prefetch ring: 4 named slots, depth 3 (tile m loaded at iter m-3)
  float4 Pa[4], Pb[4];
#pragma unroll
  for (int k = 0; k < 3; ++k) {
    Pa[k] = *(const float4*)(xb + (size_t)(k * 32 + u0) * NPIX + pxq);
    Pb[k] = *(const float4*)(xb + (size_t)(k * 32 + u1) * NPIX + pxq);
  }

  // A-frag ping-pong
  short8v aP[2][2][2];
#pragma unroll
  for (int cf = 0; cf < 2; ++cf)
#pragma unroll
    for (int ks = 0; ks < 2; ++ks)
      aP[0][cf][ks] = *(const short8v*)(wb + offA[cf][ks]);

  // stage tile 0 into buf0
  {
    unsigned wd0[4], wd1[4];
    wd0[0] = cvt_split(Pa[0].x); wd0[1] = cvt_split(Pa[0].y);
    wd0[2] = cvt_split(Pa[0].z); wd0[3] = cvt_split(Pa[0].w);
    wd1[0] = cvt_split(Pb[0].x); wd1[1] = cvt_split(Pb[0].y);
    wd1[2] = cvt_split(Pb[0].z); wd1[3] = cvt_split(Pb[0].w);
#pragma unroll
    for (int j = 0; j < 4; ++j) {
      ldsB[0][(pxq + j) * 32 + (u0 ^ sBw[j])] = wd0[j];
      ldsB[0][(pxq + j) * 32 + (u1 ^ sBw[j])] = wd1[j];
    }
  }
  asm volatile("s_waitcnt lgkmcnt(0)" ::: "memory");
  __builtin_amdgcn_s_barrier();

#pragma unroll
  for (int kst = 0; kst < 8; ++kst) {
    int cur = kst & 1;
    // issue prefetches EARLY, pin with sched_barrier
    if (kst + 3 < 8) {
      Pa[(kst + 3) & 3] = *(const float4*)(xb + (size_t)((kst + 3) * 32 + u0) * NPIX + pxq);
      Pb[(kst + 3) & 3] = *(const float4*)(xb + (size_t)((kst + 3) * 32 + u1) * NPIX + pxq);
    }
    if (kst + 1 < 8) {
#pragma unroll
      for (int cf = 0; cf < 2; ++cf)
#pragma unroll
        for (int ks = 0; ks < 2; ++ks)
          aP[(kst + 1) & 1][cf][ks] =
              *(const short8v*)(wb + (kst + 1) * 4096 + offA[cf][ks]);
    }
    __builtin_amdgcn_sched_barrier(0);

    // MFMA on current buffer
#pragma unroll
    for (int ks = 0; ks < 2; ++ks) {
      int kb = ks * 16 + l16 * 4;
#pragma unroll
      for (int pf = 0; pf < 4; ++pf) {
        int pxl = pf * 16 + llo;
        int sB = ((pxl >> 1) & 7) << 2;
        short8v bv = *(const short8v*)(&ldsB[cur][pxl * 32 + (kb ^ sB)]);
        acc[0][pf] = __builtin_amdgcn_mfma_f32_16x16x32_bf16(aP[cur][0][ks], bv, acc[0][pf], 0, 0, 0);
        acc[1][pf] = __builtin_amdgcn_mfma_f32_16x16x32_bf16(aP[cur][1][ks], bv, acc[1][pf], 0, 0, 0);
      }
    }
    // coalesced xTk2 bounce from current buffer (fire & forget store)
    if (bok) {
      uint4 o = *(const uint4*)(&ldsB[cur][brd]);
      *(uint4*)(xTbase + (size_t)kst * (NOUT * 32) + bwr) = o;
    }
    // stage next tile from regs loaded 3 iterations ago
    if (kst < 7) {
      unsigned wd0[4], wd1[4];
      wd0[0] = cvt_split(Pa[(kst + 1) & 3].x); wd0[1] = cvt_split(Pa[(kst + 1) & 3].y);
      wd0[2] = cvt_split(Pa[(kst + 1) & 3].z); wd0[3] = cvt_split(Pa[(kst + 1) & 3].w);
      wd1[0] = cvt_split(Pb[(kst + 1) & 3].x); wd1[1] = cvt_split(Pb[(kst + 1) & 3].y);
      wd1[2] = cvt_split(Pb[(kst + 1) & 3].z); wd1[3] = cvt_split(Pb[(kst + 1) & 3].w);
#pragma unroll
      for (int j = 0; j < 4; ++j) {
        ldsB[cur ^ 1][(pxq + j) * 32 + (u0 ^ sBw[j])] = wd0[j];
        ldsB[cur ^ 1][(pxq + j) * 32 + (u1 ^ sBw[j])] = wd1[j];
      }
    }
    asm volatile("s_waitcnt lgkmcnt(0)" ::: "memory");
    __builtin_amdgcn_s_barrier();
  }

  // epilogue: sign + margin->append -> swizzled LDS bytes -> bitmask words
  unsigned char* ldsS = (unsigned char*)&ldsB[0][0];   // 8192 B
  int co_b = w * 32;
  float Tv[2][4];
#pragma unroll
  for (int cf = 0; cf < 2; ++cf)
#pragma unroll
    for (int r = 0; r < 4; ++r)
      Tv[cf][r] = T1f[co_b + cf * 16 + l16 * 4 + r];

#pragma unroll
  for (int cf = 0; cf < 2; ++cf)
#pragma unroll
    for (int pf = 0; pf < 4; ++pf) {
      int px_l = pf * 16 + llo;
#pragma unroll
      for (int r = 0; r < 4; ++r) {
        int co = co_b + cf * 16 + l16 * 4 + r;
        float d = acc[cf][pf][r] - Tv[cf][r];
        bool pos = d >= 0.f;
        if (__builtin_fabsf(d) < MARGIN1) {
          unsigned idx = atomicAdd(&cnts[0], 1u);
          if (idx < FIXCAP) fix1[idx] = make_uint2((unsigned)(n * NPIX + px0 + px_l),
                                                   (unsigned)co);
          else pos = recheck_conv1(x + (size_t)n * CI * NPIX + px0 + px_l,
                                   w1f, bn1d, co);
        }
        ldsS[px_l * 128 + (co ^ ((px_l & 7) << 2))] = pos ? 1 : 0;
      }
    }
  __syncthreads();

  if (t < 64) {
    int px = t;
    const unsigned* ls = (const unsigned*)ldsS;
    u64 wd0 = 0, wd1 = 0;
#pragma unroll
    for (int k = 0; k < 16; ++k) {
      unsigned v = ls[px * 32 + (k ^ (px & 7))];
      unsigned nib = (((v & 0x01010101u) * 0x01020408u) >> 24) & 0xFu;
      wd0 |= (u64)nib << (4 * k);
    }
#pragma unroll
    for (int k = 16; k < 32; ++k) {
      unsigned v = ls[px * 32 + (k ^ (px & 7))];
      unsigned nib = (((v & 0x01010101u) * 0x01020408u) >> 24) & 0xFu;
      wd1 |= (u64)nib << (4 * (k - 16));
    }
    u64* ap = a1b + (size_t)(n * NPIX + px0 + px) * 2;
    ap[0] = wd0; ap[1] = wd1;
  }
}

// ---------------- F1: wave-parallel f64 fixup of a1b bits ----------------
__global__ __launch_bounds__(256) void fixup1_kernel(
    const float* __restrict__ x, const float* __restrict__ w1f,
    const double* __restrict__ bn1d, const uint2* __restrict__ fix1,
    const unsigned* __restrict__ cnts, u64* __restrict__ a1b) {
  unsigned cnt = cnts[0]; if (cnt > FIXCAP) cnt = FIXCAP;
  int nw = gridDim.x * 4;
  int gw = blockIdx.x * 4 + (threadIdx.x >> 6);
  int lane = threadIdx.x & 63;
  for (unsigned i = gw; i < cnt; i += nw) {
    uint2 it = fix1[i];
    int np = (int)it.x, co = (int)it.y;
    int n = np / NPIX, p = np % NPIX;
    const float* xg = x + (size_t)n * CI * NPIX + p;
    double s = 0.0;
#pragma unroll
    for (int j = 0; j < 4; ++j) {
      int ci = lane * 4 + j;
      s = fma((double)w1f[ci * 128 + co], (double)xg[(size_t)ci * NPIX], s);
    }
    for (int off = 32; off; off >>= 1) s += __shfl_down(s, off);
    if (lane == 0) {
      double val = (s - bn1d[128 + co]) * bn1d[co] + bn1d[256 + co];
      u64* ap = a1b + (size_t)np * 2 + (co >> 6);
      u64 bit = 1ull << (co & 63);
      if (val >= 0.0) atomicOr(ap, bit); else atomicAnd(ap, ~bit);
    }
  }
}

// ---------------- K2: conv2 (3x3 s2 p1, XNOR-popcount) + bn2 + sign --------
__global__ __launch_bounds__(256) void conv2_kernel(
    const u64* __restrict__ a1b, const u64* __restrict__ w2b,
    const float* __restrict__ g2, const float* __restrict__ b2,
    const float* __restrict__ m2, const float* __restrict__ v2,
    u64* __restrict__ a2b) {
  __shared__ u64 lw2[128 * 9 * 2];   // 18432 B
  int t = threadIdx.x;
  for (int k = 0; k < 9; ++k) lw2[t * 9 + k] = w2b[t * 9 + k];
  __syncthreads();

  int bid = (int)blockIdx.x;
  int l = (bid & 7) * 784 + (bid >> 3);   // XCD-contiguous p ranges
  int p = l * 4 + (t >> 6);               // 0..25087
  int lane = t & 63;
  int n = p / NOUT, r = p % NOUT;
  int ho = r / WO, wo = r % WO;

  int y0 = 0, y1 = 0;
  for (int kh = 0; kh < 3; ++kh) {
    int ih = 2 * ho - 1 + kh;
    if (ih < 0) continue;
    for (int kw = 0; kw < 3; ++kw) {
      int iw = 2 * wo - 1 + kw;
      if (iw < 0) continue;
      const u64* ap = a1b + ((size_t)(n * HH + ih) * WW + iw) * 2;
      u64 a0 = ap[0], a1v = ap[1];
      int tap = kh * 3 + kw;
      u64 wa = lw2[lane * 18 + tap * 2], wb = lw2[lane * 18 + tap * 2 + 1];
      y0 += 128 - 2 * (__popcll(a0 ^ wa) + __popcll(a1v ^ wb));
      wa = lw2[(lane + 64) * 18 + tap * 2]; wb = lw2[(lane + 64) * 18 + tap * 2 + 1];
      y1 += 128 - 2 * (__popcll(a0 ^ wa) + __popcll(a1v ^ wb));
    }
  }

  int co = lane;
  double inv = 1.0 / sqrt((double)v2[co] + 1e-5);
  bool c0 = (((double)y0 - (double)m2[co]) * ((double)g2[co] * inv) + (double)b2[co]) >= 0.0;
  co = lane + 64;
  inv = 1.0 / sqrt((double)v2[co] + 1e-5);
  bool c1 = (((double)y1 - (double)m2[co]) * ((double)g2[co] * inv) + (double)b2[co]) >= 0.0;

  u64 word0 = __ballot(c0);
  u64 word1 = __ballot(c1);
  if (lane == 0) {
    a2b[(size_t)p * 2] = word0;
    a2b[(size_t)p * 2 + 1] = word1;
  }
}

// ---------------- K3: shortcut GEMM, XCD-swizzled + coalesced output -------
// Swizzle: 896 = 8*112; cob varies fastest -> the 4 blocks sharing a B tile
// land on the SAME XCD (B fetched once/XCD). Output staged as sign bytes in
// LDS, then written as float4 with 448B-contiguous runs per co row.
__global__ __launch_bounds__(256) void sc3_mfma_kernel(
    const unsigned* __restrict__ xTk2, const unsigned* __restrict__ wsck,
    const u64* __restrict__ a2b, const u64* __restrict__ w3b,
    const float* __restrict__ bn3f,
    uint2* __restrict__ fix3, unsigned* __restrict__ cnts,
    float* __restrict__ out) {
  __shared__ unsigned ldsB2[3][4096];   // 48 KB

  int bid = (int)blockIdx.x;
  int l = (bid & 7) * 112 + (bid >> 3);
  int n = l / 28; int rr = l % 28; int pxt = rr >> 2; int cob = rr & 3;
  int px0 = pxt * 112;
  int t = threadIdx.x, w = t >> 6, lane = t & 63;
  int l16 = lane >> 4, llo = lane & 15;
  int sA = (llo & 7) << 2;
  int coL = w * 32 + llo;

  const unsigned* wb = wsck + (size_t)(cob * 128 + coL) * 32;
  int offA[2][2];
#pragma unroll
  for (int cf = 0; cf < 2; ++cf)
#pragma unroll
    for (int ks = 0; ks < 2; ++ks)
      offA[cf][ks] = cf * 512 + ((ks * 16 + l16 * 4) ^ sA);

  const unsigned* gb0 = xTk2 + ((size_t)n * 8 * NOUT + px0) * 32 + lane * 4;

  f32x4 acc[2][7] = {};
  short8v aP[2][2][2];

  // prologue: B0 -> buf0, B1 -> buf1, A0
#pragma unroll
  for (int i = 0; i < 4; ++i) {
    int idx = i * 4 + w;
    const unsigned* src = gb0 + (idx < 14 ? idx * 256 : 0);
    gload_lds16(src, &ldsB2[0][idx * 256]);
  }
#pragma unroll
  for (int i = 0; i < 4; ++i) {
    int idx = i * 4 + w;
    const unsigned* gb = gb0 + (size_t)(NOUT * 32);
    const unsigned* src = gb + (idx < 14 ? idx * 256 : 0);
    gload_lds16(src, &ldsB2[1][idx * 256]);
  }
#pragma unroll
  for (int cf = 0; cf < 2; ++cf)
#pragma unroll
    for (int ks = 0; ks < 2; ++ks)
      aP[0][cf][ks] = *(const short8v*)(wb + offA[cf][ks]);

#pragma unroll
  for (int kst = 0; kst < 8; ++kst) {
    int cur = kst % 3;
    // issue A(k+1) first, then B(k+2)
    if (kst + 1 < 8) {
#pragma unroll
      for (int cf = 0; cf < 2; ++cf)
#pragma unroll
        for (int ks = 0; ks < 2; ++ks)
          aP[(kst + 1) & 1][cf][ks] =
              *(const short8v*)(wb + (kst + 1) * 16384 + offA[cf][ks]);
    }
    if (kst + 2 < 8) {
      const unsigned* gb = gb0 + (size_t)(kst + 2) * (NOUT * 32);
#pragma unroll
      for (int i = 0; i < 4; ++i) {
        int idx = i * 4 + w;
        const unsigned* src = gb + (idx < 14 ? idx * 256 : 0);
        gload_lds16(src, &ldsB2[(kst + 2) % 3][idx * 256]);
      }
    }
    // counted wait: drain through A(k) and B(k)
    if (kst == 0) asm volatile("s_waitcnt vmcnt(8)" ::: "memory");
    else if (kst <= 5) asm volatile("s_waitcnt vmcnt(12)" ::: "memory");
    else if (kst == 6) asm volatile("s_waitcnt vmcnt(8)" ::: "memory");
    else asm volatile("s_waitcnt vmcnt(0)" ::: "memory");
    __builtin_amdgcn_s_barrier();

#pragma unroll
    for (int ks = 0; ks < 2; ++ks) {
      int kb = ks * 16 + l16 * 4;
#pragma unroll
      for (int pf = 0; pf < 7; ++pf) {
        short8v bv = *(const short8v*)(&ldsB2[cur][(pf * 16 + llo) * 32 + (kb ^ sA)]);
        acc[0][pf] = __builtin_amdgcn_mfma_f32_16x16x32_bf16(aP[kst & 1][0][ks], bv, acc[0][pf], 0, 0, 0);
        acc[1][pf] = __builtin_amdgcn_mfma_f32_16x16x32_bf16(aP[kst & 1][1][ks], bv, acc[1][pf], 0, 0, 0);
      }
    }
    __builtin_amdgcn_s_barrier();
  }

  // epilogue: conv3 popcount + fused BNs + sign -> LDS bytes -> coalesced out
  unsigned char* ldsS = (unsigned char*)&ldsB2[0][0];   // 14336 B (buf0+)
  int co_base = cob * 128 + w * 32;
  int pl[7];
  u64 a20[7], a21[7];
#pragma unroll
  for (int pf = 0; pf < 7; ++pf) {
    pl[pf] = px0 + pf * 16 + llo;
    const u64* ap = a2b + (size_t)(n * NOUT + pl[pf]) * 2;
    a20[pf] = ap[0]; a21[pf] = ap[1];
  }

#pragma unroll
  for (int cf = 0; cf < 2; ++cf) {
    float ssv[4], s3v[4], Cv[4];
    u64 w30[4], w31[4];
#pragma unroll
    for (int r = 0; r < 4; ++r) {
      int co = co_base + cf * 16 + l16 * 4 + r;
      ssv[r] = bn3f[co]; s3v[r] = bn3f[512 + co]; Cv[r] = bn3f[1024 + co];
      w30[r] = w3b[co * 2]; w31[r] = w3b[co * 2 + 1];
    }
#pragma unroll
    for (int pf = 0; pf < 7; ++pf) {
#pragma unroll
      for (int r = 0; r < 4; ++r) {
        int co = co_base + cf * 16 + l16 * 4 + r;
        int y3 = 128 - 2 * (int)(__popcll(a20[pf] ^ w30[r]) +
                                 __popcll(a21[pf] ^ w31[r]));
        float val = fmaf(acc[cf][pf][r], ssv[r],
                         fmaf((float)y3, s3v[r], Cv[r]));
        bool pos = val >= 0.f;
        if (__builtin_fabsf(val) < MARGIN3) {
          unsigned idx = atomicAdd(&cnts[1], 1u);
          if (idx < FIXCAP)
            fix3[idx] = make_uint2((unsigned)(n * NOUT + pl[pf]),
                                   (unsigned)co | ((unsigned)(y3 + 256) << 16));
        }
        int co_loc = w * 32 + cf * 16 + l16 * 4 + r;
        ldsS[co_loc * 112 + (pf * 16 + llo)] = pos ? 1 : 0;
      }
    }
  }
  __syncthreads();

  if (t < 224) {
    int f4 = t % 28, cg = t / 28;       // cg 0..7
    const unsigned* ls32 = (const unsigned*)ldsS;
#pragma unroll
    for (int j = 0; j < 16; ++j) {
      int co_loc = cg + 8 * j;
      unsigned wbyte = ls32[co_loc * 28 + f4];
      float4 o;
      o.x = (wbyte & 0xFFu) ? 1.f : -1.f;
      o.y = (wbyte & 0xFF00u) ? 1.f : -1.f;
      o.z = (wbyte & 0xFF0000u) ? 1.f : -1.f;
      o.w = (wbyte & 0xFF000000u) ? 1.f : -1.f;
      *(float4*)(out + ((size_t)(n * CO + cob * 128 + co_loc)) * NOUT
                 + px0 + f4 * 4) = o;
    }
  }
}

// ---------------- F3: wave-parallel f64 fixup of out values ----------------
__global__ __launch_bounds__(256) void fixup3_kernel(
    const float* __restrict__ x, const float* __restrict__ wscf,
    const double* __restrict__ bn3d, const uint2* __restrict__ fix3,
    const unsigned* __restrict__ cnts, float* __restrict__ out) {
  unsigned cnt = cnts[1]; if (cnt > FIXCAP) cnt = FIXCAP;
  int nw = gridDim.x * 4;
  int gw = blockIdx.x * 4 + (threadIdx.x >> 6);
  int lane = threadIdx.x & 63;
  for (unsigned i = gw; i < cnt; i += nw) {
    uint2 it = fix3[i];
    int npl = (int)it.x;
    int co = (int)(it.y & 0xFFFFu);
    int y3 = (int)(it.y >> 16) - 256;
    int n = npl / NOUT, pl = npl % NOUT;
    int ho = pl / WO, wo = pl % WO;
    const float* xg = x + (size_t)n * CI * NPIX + ho * 112 + wo * 2;
    double s = 0.0;
#pragma unroll
    for (int j = 0; j < 4; ++j) {
      int ci = lane * 4 + j;
      s = fma((double)wscf[ci * 512 + co], (double)xg[(size_t)ci * NPIX], s);
    }
    for (int off = 32; off; off >>= 1) s += __shfl_down(s, off);
    if (lane == 0) {
      double val = s * bn3d[co] + (double)y3 * bn3d[512 + co] + bn3d[1024 + co];
      out[(size_t)(n * CO + co) * NOUT + pl] = (val >= 0.0) ? 1.0f : -1.0f;
    }
  }
}

// ================= fallback (R2) f32-VALU kernels =================
__global__ __launch_bounds__(256) void conv1_kernel(
    const float* __restrict__ x, const float* __restrict__ w1f,
    const float* __restrict__ T1f, const double* __restrict__ bn1d,
    u64* __restrict__ a1b) {
  __shared__ float4 xrow4[128 * WW / 4];
  __shared__ unsigned char pk[WW * 32];
  float* xrow = (float*)xrow4;

  int bid = blockIdx.x;
  int n = bid / HH, h = bid % HH;
  int t = threadIdx.x;
  int cg = t & 31, wg = t >> 5;
  int co0 = cg * 4, w0 = wg * 7;

  float acc[4][7];
#pragma unroll
  for (int c = 0; c < 4; ++c)
#pragma unroll
    for (int j = 0; j < 7; ++j) acc[c][j] = 0.f;

  for (int chunk = 0; chunk < 2; ++chunk) {
    const float4* xsrc = (const float4*)(x + (size_t)n * CI * NPIX
                                         + (size_t)chunk * 128 * NPIX + h * WW);
    for (int i = 0; i < 7; ++i) {
      int idx = i * 256 + t;
      int ci = idx / 14, f = idx % 14;
      xrow4[ci * 14 + f] = xsrc[(size_t)ci * (NPIX / 4) + f];
    }
    __syncthreads();

    const float* wp = w1f + (size_t)chunk * 128 * 128 + co0;
#pragma unroll 2
    for (int ci = 0; ci < 128; ++ci) {
      float4 wv = *(const float4*)(wp + ci * 128);
      const float* xr = xrow + ci * WW + w0;
#pragma unroll
      for (int j = 0; j < 7; ++j) {
        float xv = xr[j];
        acc[0][j] = fmaf(wv.x, xv, acc[0][j]);
        acc[1][j] = fmaf(wv.y, xv, acc[1][j]);
        acc[2][j] = fmaf(wv.z, xv, acc[2][j]);
        acc[3][j] = fmaf(wv.w, xv, acc[3][j]);
      }
    }
    __syncthreads();
  }

  float Tv[4];
#pragma unroll
  for (int c = 0; c < 4; ++c) Tv[c] = T1f[co0 + c];

  for (int j = 0; j < 7; ++j) {
    unsigned nib = 0;
    for (int c = 0; c < 4; ++c) {
      float d = acc[c][j] - Tv[c];
      bool pos;
      if (__builtin_fabsf(d) >= 1e-2f) pos = d >= 0.f;
      else pos = recheck_conv1(x + (size_t)n * CI * NPIX + h * WW + (w0 + j),
                               w1f, bn1d, co0 + c);
      nib |= ((unsigned)pos) << c;
    }
    pk[(w0 + j) * 32 + cg] = (unsigned char)nib;
  }
  __syncthreads();

  if (t < 112) {
    int w = t >> 1, half = t & 1;
    u64 word = 0;
    for (int k = 0; k < 16; ++k)
      word |= ((u64)pk[w * 32 + half * 16 + k]) << (4 * k);
    a1b[((size_t)(n * HH + h) * WW + w) * 2 + half] = word;
  }
}

__global__ __launch_bounds__(256) void sc3_kernel(
    const float* __restrict__ x, const float* __restrict__ wscf,
    const u64* __restrict__ a2b, const u64* __restrict__ w3b,
    const float* __restrict__ bn3f, const double* __restrict__ bn3d,
    float* __restrict__ out) {
  __shared__ float4 xrow4[128 * WW / 4];
  __shared__ u64 a2row[WO * 2];
  float* xrow = (float*)xrow4;

  int bid = blockIdx.x;
  int half = bid & 1;
  int tmp = bid >> 1;
  int n = tmp / HO, ho = tmp % HO;
  int t = threadIdx.x;
  int cg = t & 63, wg = t >> 6;
  int co0 = half * 256 + cg * 4, w0 = wg * 7;

  if (t < 56)
    a2row[t] = a2b[((size_t)(n * HO + ho) * WO + (t >> 1)) * 2 + (t & 1)];

  float acc[4][7];
#pragma unroll
  for (int c = 0; c < 4; ++c)
#pragma unroll
    for (int j = 0; j < 7; ++j) acc[c][j] = 0.f;

  for (int chunk = 0; chunk < 2; ++chunk) {
    const float4* xsrc = (const float4*)(x + (size_t)n * CI * NPIX
                                         + (size_t)chunk * 128 * NPIX
                                         + (2 * ho) * WW);
    for (int i = 0; i < 7; ++i) {
      int idx = i * 256 + t;
      int ci = idx / 14, f = idx % 14;
      xrow4[ci * 14 + f] = xsrc[(size_t)ci * (NPIX / 4) + f];
    }
    __syncthreads();

    const float* wp = wscf + (size_t)chunk * 128 * 512 + co0;
#pragma unroll 2
    for (int ci = 0; ci < 128; ++ci) {
      float4 wv = *(const float4*)(wp + ci * 512);
      const float* xr = xrow + ci * WW + 2 * w0;
#pragma unroll
      for (int j = 0; j < 7; ++j) {
        float xv = xr[2 * j];
        acc[0][j] = fmaf(wv.x, xv, acc[0][j]);
        acc[1][j] = fmaf(wv.y, xv, acc[1][j]);
        acc[2][j] = fmaf(wv.z, xv, acc[2][j]);
        acc[3][j] = fmaf(wv.w, xv, acc[3][j]);
      }
    }
    __syncthreads();
  }

#pragma unroll
  for (int c = 0; c < 4; ++c) {
    int co = co0 + c;
    u64 w30 = w3b[co * 2], w31 = w3b[co * 2 + 1];
    float ssf = bn3f[co], s3f = bn3f[512 + co], Cf = bn3f[1024 + co];
    float* op = out + ((size_t)(n * CO + co) * NOUT) + ho * WO + w0;
    for (int j = 0; j < 7; ++j) {
      int wo = w0 + j;
      u64 a0 = a2row[wo * 2], a1v = a2row[wo * 2 + 1];
      int y3 = 128 - 2 * (int)(__popcll(a0 ^ w30) + __popcll(a1v ^ w31));
      float val = fmaf(acc[c][j], ssf, fmaf((float)y3, s3f, Cf));
      bool pos;
      if (__builtin_fabsf(val) >= 2e-2f) pos = val >= 0.f;
      else pos = recheck_sc3(x + (size_t)n * CI * NPIX + (2 * ho) * WW + 2 * wo,
                             wscf, bn3d, co, y3);
      op[j] = pos ? 1.0f : -1.0f;
    }
  }
}

extern "C" void kernel_launch(void* const* d_in, const int* in_sizes, int n_in,
                              void* d_out, int out_size, void* d_ws, size_t ws_size,
                              hipStream_t stream) {
  const float* x   = (const float*)d_in[0];
  const float* W1  = (const float*)d_in[1];
  const float* W2  = (const float*)d_in[2];
  const float* W3  = (const float*)d_in[3];
  const float* Wsc = (const float*)d_in[4];
  const float* g1 = (const float*)d_in[5],  *b1 = (const float*)d_in[6];
  const float* m1 = (const float*)d_in[7],  *v1 = (const float*)d_in[8];
  const float* g2 = (const float*)d_in[9],  *b2 = (const float*)d_in[10];
  const float* m2 = (const float*)d_in[11], *v2 = (const float*)d_in[12];
  const float* g3 = (const float*)d_in[13], *b3 = (const float*)d_in[14];
  const float* m3 = (const float*)d_in[15], *v3 = (const float*)d_in[16];
  const float* gs = (const float*)d_in[17], *bs = (const float*)d_in[18];
  const float* ms = (const float*)d_in[19], *vs = (const float*)d_in[20];

  char* ws = (char*)d_ws;
  float*  w1f  = (float*)(ws + 0);           // 131072
  float*  wscf = (float*)(ws + 131072);      // 524288
  u64*    a1b  = (u64*)(ws + 655360);        // 1605632
  u64*    a2b  = (u64*)(ws + 2260992);       // 401408
  u64*    w2b  = (u64*)(ws + 2662400);       // 18432
  u64*    w3b  = (u64*)(ws + 2680832);       // 8192
  float*  T1f  = (float*)(ws + 2689024);     // 512
  double* bn1d = (double*)(ws + 2689536);    // 3072
  float*  bn3f = (float*)(ws + 2692608);     // 6144
  double* bn3d = (double*)(ws + 2698752);    // 12288
  unsigned* w1k  = (unsigned*)(ws + 2711040);    // 131072
  unsigned* wsck = (unsigned*)(ws + 2842112);    // 524288
  unsigned* xTk2 = (unsigned*)(ws + 3366400);    // 25690112
  uint2*    fix1 = (uint2*)(ws + 29056512);      // 524288
  uint2*    fix3 = (uint2*)(ws + 29580800);      // 524288
  unsigned* cnts = (unsigned*)(ws + 30105088);   // 256
  const size_t required = 30105344ull;           // ~28.7 MiB
  float* out = (float*)d_out;

  bool mfma_path = (ws_size >= required);
  if (!mfma_path) {   // alias mfma-only arrays into a1b region (unused then)
    w1k  = (unsigned*)a1b;
    wsck = (unsigned*)a1b + 32768;
    cnts = (unsigned*)a1b + 32768 + 131072;
  }

  hipLaunchKernelGGL(pack_kernel, dim3(2115), dim3(256), 0, stream,
                     W1, W2, W3, Wsc, g1, b1, m1, v1, g3, b3, m3, v3,
                     gs, bs, ms, vs, w1f, wscf, w2b, w3b, T1f, bn1d, bn3f, bn3d,
                     w1k, wsck, cnts);
  if (mfma_path) {
    hipLaunchKernelGGL(conv1_mfma_kernel, dim3(NB * 49), dim3(256), 0, stream,
                       x, w1k, w1f, T1f, bn1d, fix1, cnts, a1b, xTk2);
    hipLaunchKernelGGL(fixup1_kernel, dim3(256), dim3(256), 0, stream,
                       x, w1f, bn1d, fix1, cnts, a1b);
    hipLaunchKernelGGL(conv2_kernel, dim3(NB * NOUT / 4), dim3(256), 0, stream,
                       a1b, w2b, g2, b2, m2, v2, a2b);
    hipLaunchKernelGGL(sc3_mfma_kernel, dim3(NB * 7 * 4), dim3(256), 0, stream,
                       xTk2, wsck, a2b, w3b, bn3f, fix3, cnts, out);
    hipLaunchKernelGGL(fixup3_kernel, dim3(256), dim3(256), 0, stream,
                       x, wscf, bn3d, fix3, cnts, out);
  } else {
    hipLaunchKernelGGL(conv1_kernel, dim3(NB * HH), dim3(256), 0, stream,
                       x, w1f, T1f, bn1d, a1b);
    hipLaunchKernelGGL(conv2_kernel, dim3(NB * NOUT / 4), dim3(256), 0, stream,
                       a1b, w2b, g2, b2, m2, v2, a2b);
    hipLaunchKernelGGL(sc3_kernel, dim3(NB * HO * 2), dim3(256), 0, stream,
                       x, wscf, a2b, w3b, bn3f, bn3d, out);
  }
}